// Round 1
// baseline (139.644 us; speedup 1.0000x reference)
//
#include <hip/hip_runtime.h>

// WisePooling: per-segment column mean + EPS.
// x: (N, D=512) fp32; graph: (S, 2) int32 rows [start, end] inclusive.
// out: (S, D) fp32 = mean(x[start..end], axis=0) + EPS.

#define EPS_VAL 0.006f
#define DIM 512
#define DV (DIM / 4)  // 128 float4 per row

__global__ __launch_bounds__(128) void wise_pooling_kernel(
    const float* __restrict__ x,
    const int* __restrict__ graph,
    float* __restrict__ out,
    int S) {
  const int s = blockIdx.x;
  if (s >= S) return;

  const int start = graph[2 * s];
  const int end   = graph[2 * s + 1];
  const int count = end - start + 1;

  const int t = threadIdx.x;  // 0..127, one float4 column-slice per thread
  const float4* xp = reinterpret_cast<const float4*>(x) + (size_t)start * DV + t;

  float4 acc = make_float4(0.f, 0.f, 0.f, 0.f);

  int r = 0;
  // Unroll x4: four independent 16B loads in flight per thread.
  for (; r + 4 <= count; r += 4) {
    float4 a = xp[0 * DV];
    float4 b = xp[1 * DV];
    float4 c = xp[2 * DV];
    float4 d = xp[3 * DV];
    acc.x += (a.x + b.x) + (c.x + d.x);
    acc.y += (a.y + b.y) + (c.y + d.y);
    acc.z += (a.z + b.z) + (c.z + d.z);
    acc.w += (a.w + b.w) + (c.w + d.w);
    xp += 4 * DV;
  }
  for (; r < count; ++r) {
    float4 a = *xp;
    acc.x += a.x;
    acc.y += a.y;
    acc.z += a.z;
    acc.w += a.w;
    xp += DV;
  }

  const float inv = 1.0f / (float)count;
  float4 res;
  res.x = acc.x * inv + EPS_VAL;
  res.y = acc.y * inv + EPS_VAL;
  res.z = acc.z * inv + EPS_VAL;
  res.w = acc.w * inv + EPS_VAL;

  reinterpret_cast<float4*>(out)[(size_t)s * DV + t] = res;
}

extern "C" void kernel_launch(void* const* d_in, const int* in_sizes, int n_in,
                              void* d_out, int out_size, void* d_ws, size_t ws_size,
                              hipStream_t stream) {
  const float* x = (const float*)d_in[0];
  const int* graph = (const int*)d_in[1];
  float* out = (float*)d_out;

  const int S = in_sizes[1] / 2;  // graph has S*2 ints

  dim3 grid(S);
  dim3 block(128);
  wise_pooling_kernel<<<grid, block, 0, stream>>>(x, graph, out, S);
}

// Round 2
// 134.688 us; speedup vs baseline: 1.0368x; 1.0368x over previous
//
#include <hip/hip_runtime.h>

// WisePooling: per-segment column mean + EPS.
// x: (N, D=512) fp32; graph: (S, 2) int32 [start, end] inclusive, starts/ends sorted.
// out[s] = mean(x[start_s..end_s], axis=0) + EPS.
//
// Balanced decomposition: one block per 32-row tile of x (contiguous streaming
// reads, perfect load balance). Each block finds segments overlapping its tile
// (binary search on sorted ends), accumulates the intersection rows, and
// commits partial means: plain store when the segment lies fully inside the
// tile, fp32 atomics otherwise. The tile containing start_s adds EPS (exactly
// one tile per segment; handles degenerate duplicate segments too).

#define EPS_VAL 0.006f
#define DIM 512
#define DV 128   // float4 per row
#define TILE 32  // rows per block

__global__ __launch_bounds__(256) void zero_out_kernel(float4* __restrict__ out, int n4) {
  int i = blockIdx.x * 256 + threadIdx.x;
  if (i < n4) out[i] = make_float4(0.f, 0.f, 0.f, 0.f);
}

__global__ __launch_bounds__(128) void pool_tile_kernel(
    const float* __restrict__ x,
    const int* __restrict__ graph,
    float* __restrict__ out,
    int N, int S) {
  const int r0 = blockIdx.x * TILE;
  const int r1m1 = min(r0 + TILE, N) - 1;  // last row of tile, inclusive
  const int t = threadIdx.x;               // 0..127: one float4 column slice

  // First segment whose end >= r0 (ends are non-decreasing).
  int lo = 0, hi = S - 1;
  while (lo < hi) {
    int mid = (lo + hi) >> 1;
    if (graph[2 * mid + 1] < r0) lo = mid + 1; else hi = mid;
  }

  for (int s = lo; s < S; ++s) {
    const int st = graph[2 * s];
    if (st > r1m1) break;
    const int en = graph[2 * s + 1];
    const int rA = st > r0 ? st : r0;
    const int rB = en < r1m1 ? en : r1m1;
    if (rB < rA) continue;  // defensive; shouldn't happen

    float4 acc = make_float4(0.f, 0.f, 0.f, 0.f);
    const float4* xp = reinterpret_cast<const float4*>(x) + (size_t)rA * DV + t;
    int r = rA;
    for (; r + 4 <= rB + 1; r += 4) {
      float4 a = xp[0 * DV];
      float4 b = xp[1 * DV];
      float4 c = xp[2 * DV];
      float4 d = xp[3 * DV];
      acc.x += (a.x + b.x) + (c.x + d.x);
      acc.y += (a.y + b.y) + (c.y + d.y);
      acc.z += (a.z + b.z) + (c.z + d.z);
      acc.w += (a.w + b.w) + (c.w + d.w);
      xp += 4 * DV;
    }
    for (; r <= rB; ++r) {
      float4 a = *xp;
      acc.x += a.x; acc.y += a.y; acc.z += a.z; acc.w += a.w;
      xp += DV;
    }

    const float inv = 1.0f / (float)(en - st + 1);
    float4 res;
    res.x = acc.x * inv; res.y = acc.y * inv;
    res.z = acc.z * inv; res.w = acc.w * inv;
    const bool owns_start = (st >= r0);  // exactly one tile per segment
    if (owns_start) {
      res.x += EPS_VAL; res.y += EPS_VAL; res.z += EPS_VAL; res.w += EPS_VAL;
    }

    float* op = out + (size_t)s * DIM + t * 4;
    if (owns_start && en <= r1m1) {
      // segment fully inside this tile: sole contributor, plain store
      *reinterpret_cast<float4*>(op) = res;
    } else {
      unsafeAtomicAdd(op + 0, res.x);
      unsafeAtomicAdd(op + 1, res.y);
      unsafeAtomicAdd(op + 2, res.z);
      unsafeAtomicAdd(op + 3, res.w);
    }
  }
}

extern "C" void kernel_launch(void* const* d_in, const int* in_sizes, int n_in,
                              void* d_out, int out_size, void* d_ws, size_t ws_size,
                              hipStream_t stream) {
  const float* x = (const float*)d_in[0];
  const int* graph = (const int*)d_in[1];
  float* out = (float*)d_out;

  const int N = in_sizes[0] / DIM;
  const int S = in_sizes[1] / 2;

  const int n4 = out_size / 4;  // float4 count
  zero_out_kernel<<<(n4 + 255) / 256, 256, 0, stream>>>(
      reinterpret_cast<float4*>(out), n4);

  const int ntiles = (N + TILE - 1) / TILE;
  pool_tile_kernel<<<ntiles, 128, 0, stream>>>(x, graph, out, N, S);
}

// Round 3
// 129.634 us; speedup vs baseline: 1.0772x; 1.0390x over previous
//
#include <hip/hip_runtime.h>

// WisePooling: per-segment column mean + EPS.
// x: (N, D=512) fp32; graph: (S, 2) int32 [start, end] inclusive, starts/ends sorted.
// out[s] = mean(x[start_s..end_s], axis=0) + EPS.
//
// One block per 32-row tile. Uniform, fully-unrolled streaming loop over the
// tile's rows (groups of 4, rotated prefetch so the next group's loads are in
// flight while the current group accumulates). Segment commits happen inside
// the loop on a wave-uniform branch; boundary-crossing segments combine via
// fp32 atomics onto a zeroed output. The tile owning seg.start adds EPS.
// Degenerate duplicate segments ([c,c] sharing a row with the next segment)
// are handled by the while-commit with acc re-seeded to the row value.

#define EPS_VAL 0.006f
#define DIM 512
#define DV 128   // float4 per row
#define TILE 32  // rows per block (N % TILE == 0 for this problem)
#define GROUP 4
#define NGROUPS (TILE / GROUP)

__global__ __launch_bounds__(256) void zero_out_kernel(float4* __restrict__ out, int n4) {
  int i = blockIdx.x * 256 + threadIdx.x;
  if (i < n4) out[i] = make_float4(0.f, 0.f, 0.f, 0.f);
}

__global__ __launch_bounds__(128) void pool_tile_kernel(
    const float* __restrict__ x,
    const int* __restrict__ graph,
    float* __restrict__ out,
    int N, int S) {
  const int r0 = blockIdx.x * TILE;
  const int r1 = r0 + TILE - 1;  // last row of tile (N % TILE == 0)
  const int t = threadIdx.x;     // 0..127: one float4 column slice

  // First segment whose end >= r0 (ends are non-decreasing).
  int lo = 0, hi = S - 1;
  while (lo < hi) {
    int mid = (lo + hi) >> 1;
    if (graph[2 * mid + 1] < r0) lo = mid + 1; else hi = mid;
  }

  int s = lo;
  int seg_st = graph[2 * s];
  int seg_en = graph[2 * s + 1];
  int nx_st = (s + 1 < S) ? graph[2 * s + 2] : N;
  int nx_en = (s + 1 < S) ? graph[2 * s + 3] : N;

  const float4* xp = reinterpret_cast<const float4*>(x) + (size_t)r0 * DV + t;

  float4 acc = make_float4(0.f, 0.f, 0.f, 0.f);
  float4 buf[GROUP];
#pragma unroll
  for (int j = 0; j < GROUP; ++j) buf[j] = xp[j * DV];
  xp += GROUP * DV;

#pragma unroll
  for (int g = 0; g < NGROUPS; ++g) {
    float4 nbuf[GROUP];
    if (g + 1 < NGROUPS) {
#pragma unroll
      for (int j = 0; j < GROUP; ++j) nbuf[j] = xp[j * DV];
      xp += GROUP * DV;
    }
#pragma unroll
    for (int j = 0; j < GROUP; ++j) {
      const int r = r0 + g * GROUP + j;
      const float4 v = buf[j];
      acc.x += v.x; acc.y += v.y; acc.z += v.z; acc.w += v.w;
      // Wave-uniform commit branch: r and seg_en are block-uniform.
      while (r == seg_en) {
        const float inv = 1.0f / (float)(seg_en - seg_st + 1);
        float4 res;
        res.x = acc.x * inv; res.y = acc.y * inv;
        res.z = acc.z * inv; res.w = acc.w * inv;
        float* op = out + (size_t)s * DIM + t * 4;
        if (seg_st >= r0) {
          // Segment fully inside this tile: sole contributor + EPS owner.
          res.x += EPS_VAL; res.y += EPS_VAL; res.z += EPS_VAL; res.w += EPS_VAL;
          *reinterpret_cast<float4*>(op) = res;
        } else {
          unsafeAtomicAdd(op + 0, res.x);
          unsafeAtomicAdd(op + 1, res.y);
          unsafeAtomicAdd(op + 2, res.z);
          unsafeAtomicAdd(op + 3, res.w);
        }
        ++s;
        seg_st = nx_st; seg_en = nx_en;
        if (s + 1 < S) {
          nx_st = graph[2 * s + 2];
          nx_en = graph[2 * s + 3];
        } else {
          nx_st = N; nx_en = N;
        }
        // Overlapping start (degenerate duplicate chain): re-seed with row r.
        if (seg_st <= r) { acc = v; } else { acc = make_float4(0.f, 0.f, 0.f, 0.f); }
      }
    }
#pragma unroll
    for (int j = 0; j < GROUP; ++j) buf[j] = nbuf[j];
  }

  // Tail: current segment extends past the tile -> atomic partial.
  if (s < S && seg_st <= r1) {
    const float inv = 1.0f / (float)(seg_en - seg_st + 1);
    float4 res;
    res.x = acc.x * inv; res.y = acc.y * inv;
    res.z = acc.z * inv; res.w = acc.w * inv;
    if (seg_st >= r0) {  // EPS owner
      res.x += EPS_VAL; res.y += EPS_VAL; res.z += EPS_VAL; res.w += EPS_VAL;
    }
    float* op = out + (size_t)s * DIM + t * 4;
    unsafeAtomicAdd(op + 0, res.x);
    unsafeAtomicAdd(op + 1, res.y);
    unsafeAtomicAdd(op + 2, res.z);
    unsafeAtomicAdd(op + 3, res.w);
  }
}

extern "C" void kernel_launch(void* const* d_in, const int* in_sizes, int n_in,
                              void* d_out, int out_size, void* d_ws, size_t ws_size,
                              hipStream_t stream) {
  const float* x = (const float*)d_in[0];
  const int* graph = (const int*)d_in[1];
  float* out = (float*)d_out;

  const int N = in_sizes[0] / DIM;
  const int S = in_sizes[1] / 2;

  const int n4 = out_size / 4;  // float4 count
  zero_out_kernel<<<(n4 + 255) / 256, 256, 0, stream>>>(
      reinterpret_cast<float4*>(out), n4);

  const int ntiles = N / TILE;
  pool_tile_kernel<<<ntiles, 128, 0, stream>>>(x, graph, out, N, S);
}

// Round 5
// 123.118 us; speedup vs baseline: 1.1342x; 1.0529x over previous
//
#include <hip/hip_runtime.h>

// WisePooling: per-segment column mean + EPS.
// x: (N, D=512) fp32; graph: (S, 2) int32 [start, end] inclusive, starts/ends sorted.
// out[s] = mean(x[start_s..end_s], axis=0) + EPS.
//
// One block per 32-row tile; 128 threads = one float4 column slice each.
// init_kernel zeros out[] and precomputes per-tile first-overlapping-segment
// lo[] (binary search, massively parallel). pool_tile_kernel stages the tile's
// segment descriptors into LDS (commit path touches lgkmcnt only, keeping the
// vmcnt queue pure row-data), then streams the 32 rows with 8-deep rotated
// nontemporal prefetch. Segment commits are wave-uniform branches inside the
// stream; boundary-crossing segments combine via fp32 atomics on the zeroed
// output (out stays L2-resident because x loads are nontemporal).

#define EPS_VAL 0.006f
#define DIM 512
#define DV 128     // float4 per row
#define TILE 32    // rows per block (N % TILE == 0 here)
#define GROUP 8
#define NGROUPS (TILE / GROUP)
#define MAXSEG 16  // LDS descriptor window; P(>16 cuts in 32 rows) ~ 1e-13

typedef float f32x4 __attribute__((ext_vector_type(4)));

__global__ __launch_bounds__(256) void init_kernel(
    f32x4* __restrict__ out, int n4,
    const int* __restrict__ graph, int* __restrict__ lo_arr,
    int ntiles, int S) {
  const int i = blockIdx.x * 256 + threadIdx.x;
  if (i < n4) out[i] = (f32x4){0.f, 0.f, 0.f, 0.f};
  if (i < ntiles) {
    const int r0 = i * TILE;
    int lo = 0, hi = S - 1;
    while (lo < hi) {
      int mid = (lo + hi) >> 1;
      if (graph[2 * mid + 1] < r0) lo = mid + 1; else hi = mid;
    }
    lo_arr[i] = lo;
  }
}

__global__ __launch_bounds__(128) void pool_tile_kernel(
    const float* __restrict__ x,
    const int* __restrict__ graph,
    const int* __restrict__ lo_arr,
    float* __restrict__ out,
    int N, int S) {
  __shared__ int2 sdesc[MAXSEG];
  const int r0 = blockIdx.x * TILE;
  const int r1 = r0 + TILE - 1;
  const int t = threadIdx.x;  // 0..127

  const int lo = lo_arr[blockIdx.x];
  if (t < MAXSEG) {
    const int si = lo + t;
    sdesc[t] = (si < S) ? reinterpret_cast<const int2*>(graph)[si]
                        : make_int2(N, N);
  }
  __syncthreads();

  int s = lo;
  int seg_st = sdesc[0].x;
  int seg_en = sdesc[0].y;

  const f32x4* xp = reinterpret_cast<const f32x4*>(x) + (size_t)r0 * DV + t;

  f32x4 acc = (f32x4){0.f, 0.f, 0.f, 0.f};
  f32x4 buf[GROUP];
#pragma unroll
  for (int j = 0; j < GROUP; ++j) buf[j] = __builtin_nontemporal_load(xp + j * DV);
  xp += GROUP * DV;

#pragma unroll
  for (int g = 0; g < NGROUPS; ++g) {
    f32x4 nbuf[GROUP];
    if (g + 1 < NGROUPS) {
#pragma unroll
      for (int j = 0; j < GROUP; ++j) nbuf[j] = __builtin_nontemporal_load(xp + j * DV);
      xp += GROUP * DV;
    }
#pragma unroll
    for (int j = 0; j < GROUP; ++j) {
      const int r = r0 + g * GROUP + j;
      const f32x4 v = buf[j];
      acc += v;
      // Wave-uniform commit branch (r, seg_en are block-uniform).
      while (r == seg_en) {
        const float inv = 1.0f / (float)(seg_en - seg_st + 1);
        f32x4 res = acc * inv;
        float* op = out + (size_t)s * DIM + t * 4;
        if (seg_st >= r0) {
          // Fully inside this tile: sole contributor + EPS owner.
          res += EPS_VAL;
          *reinterpret_cast<f32x4*>(op) = res;
        } else {
          unsafeAtomicAdd(op + 0, res.x);
          unsafeAtomicAdd(op + 1, res.y);
          unsafeAtomicAdd(op + 2, res.z);
          unsafeAtomicAdd(op + 3, res.w);
        }
        ++s;
        const int widx = s - lo;
        int2 nx;
        if (widx < MAXSEG) {
          nx = sdesc[widx];  // LDS: lgkmcnt, does not disturb the vmcnt queue
        } else {
          nx = (s < S) ? reinterpret_cast<const int2*>(graph)[s]
                       : make_int2(N, N);  // cold fallback, ~never taken
        }
        seg_st = nx.x; seg_en = nx.y;
        // Overlapping start (degenerate duplicate chain): re-seed with row r.
        if (seg_st <= r) { acc = v; }
        else { acc = (f32x4){0.f, 0.f, 0.f, 0.f}; }
      }
    }
#pragma unroll
    for (int j = 0; j < GROUP; ++j) buf[j] = nbuf[j];
  }

  // Tail: current segment extends past the tile -> atomic partial.
  if (s < S && seg_st <= r1) {
    const float inv = 1.0f / (float)(seg_en - seg_st + 1);
    f32x4 res = acc * inv;
    if (seg_st >= r0) {  // EPS owner
      res += EPS_VAL;
    }
    float* op = out + (size_t)s * DIM + t * 4;
    unsafeAtomicAdd(op + 0, res.x);
    unsafeAtomicAdd(op + 1, res.y);
    unsafeAtomicAdd(op + 2, res.z);
    unsafeAtomicAdd(op + 3, res.w);
  }
}

extern "C" void kernel_launch(void* const* d_in, const int* in_sizes, int n_in,
                              void* d_out, int out_size, void* d_ws, size_t ws_size,
                              hipStream_t stream) {
  const float* x = (const float*)d_in[0];
  const int* graph = (const int*)d_in[1];
  float* out = (float*)d_out;
  int* lo_arr = (int*)d_ws;  // ntiles ints = 32 KB scratch

  const int N = in_sizes[0] / DIM;
  const int S = in_sizes[1] / 2;
  const int ntiles = N / TILE;
  const int n4 = out_size / 4;

  const int init_items = (n4 > ntiles) ? n4 : ntiles;
  init_kernel<<<(init_items + 255) / 256, 256, 0, stream>>>(
      reinterpret_cast<f32x4*>(out), n4, graph, lo_arr, ntiles, S);

  pool_tile_kernel<<<ntiles, 128, 0, stream>>>(x, graph, lo_arr, out, N, S);
}

// Round 6
// 107.859 us; speedup vs baseline: 1.2947x; 1.1415x over previous
//
#include <hip/hip_runtime.h>

// WisePooling: per-segment column mean + EPS.
// x: (N, D=512) fp32; graph: (S, 2) int32 [start, end] inclusive, starts/ends sorted.
// out[s] = mean(x[start_s..end_s], axis=0) + EPS.
//
// One block per 128-row tile; 128 threads = one float4 column slice each.
// 2048 blocks = exactly 8 per CU, all co-resident (VGPR capped via
// __launch_bounds__). init_kernel zeros out[] and precomputes per-tile
// first-overlapping-segment lo[]. pool_tile_kernel stages the tile's segment
// descriptors into LDS (commit path is lgkmcnt-only; vmcnt queue stays pure
// row data), then streams 128 rows with 8-deep rotated nontemporal prefetch.
// Segment commits are wave-uniform branches inside the stream; the few
// boundary-crossing segments combine via fp32 atomics on the zeroed output.

#define EPS_VAL 0.006f
#define DIM 512
#define DV 128     // float4 per row
#define TILE 128   // rows per block (N % TILE == 0 here)
#define GROUP 8
#define NGROUPS (TILE / GROUP)
#define MAXSEG 64  // LDS descriptor window; P(Poisson(4) > 64) ~ 0

typedef float f32x4 __attribute__((ext_vector_type(4)));

__global__ __launch_bounds__(256) void init_kernel(
    f32x4* __restrict__ out, int n4,
    const int* __restrict__ graph, int* __restrict__ lo_arr,
    int ntiles, int S) {
  const int i = blockIdx.x * 256 + threadIdx.x;
  if (i < n4) out[i] = (f32x4){0.f, 0.f, 0.f, 0.f};
  if (i < ntiles) {
    const int r0 = i * TILE;
    int lo = 0, hi = S - 1;
    while (lo < hi) {
      int mid = (lo + hi) >> 1;
      if (graph[2 * mid + 1] < r0) lo = mid + 1; else hi = mid;
    }
    lo_arr[i] = lo;
  }
}

__global__ __launch_bounds__(128, 4) void pool_tile_kernel(
    const float* __restrict__ x,
    const int* __restrict__ graph,
    const int* __restrict__ lo_arr,
    float* __restrict__ out,
    int N, int S) {
  __shared__ int2 sdesc[MAXSEG];
  const int r0 = blockIdx.x * TILE;
  const int r1 = r0 + TILE - 1;
  const int t = threadIdx.x;  // 0..127

  const int lo = lo_arr[blockIdx.x];
  if (t < MAXSEG) {
    const int si = lo + t;
    sdesc[t] = (si < S) ? reinterpret_cast<const int2*>(graph)[si]
                        : make_int2(N, N);
  }
  __syncthreads();

  int s = lo;
  int seg_st = sdesc[0].x;
  int seg_en = sdesc[0].y;

  const f32x4* xp = reinterpret_cast<const f32x4*>(x) + (size_t)r0 * DV + t;

  f32x4 acc = (f32x4){0.f, 0.f, 0.f, 0.f};
  f32x4 buf[GROUP];
#pragma unroll
  for (int j = 0; j < GROUP; ++j) buf[j] = __builtin_nontemporal_load(xp + j * DV);
  xp += GROUP * DV;

#pragma unroll
  for (int g = 0; g < NGROUPS; ++g) {
    f32x4 nbuf[GROUP];
    if (g + 1 < NGROUPS) {
#pragma unroll
      for (int j = 0; j < GROUP; ++j) nbuf[j] = __builtin_nontemporal_load(xp + j * DV);
      xp += GROUP * DV;
    }
#pragma unroll
    for (int j = 0; j < GROUP; ++j) {
      const int r = r0 + g * GROUP + j;
      const f32x4 v = buf[j];
      acc += v;
      // Wave-uniform commit branch (r, seg_en are block-uniform).
      while (r == seg_en) {
        const float inv = 1.0f / (float)(seg_en - seg_st + 1);
        f32x4 res = acc * inv;
        float* op = out + (size_t)s * DIM + t * 4;
        if (seg_st >= r0) {
          // Fully inside this tile: sole contributor + EPS owner.
          res += EPS_VAL;
          *reinterpret_cast<f32x4*>(op) = res;
        } else {
          unsafeAtomicAdd(op + 0, res.x);
          unsafeAtomicAdd(op + 1, res.y);
          unsafeAtomicAdd(op + 2, res.z);
          unsafeAtomicAdd(op + 3, res.w);
        }
        ++s;
        const int widx = s - lo;
        int2 nx;
        if (widx < MAXSEG) {
          nx = sdesc[widx];  // LDS: lgkmcnt only, vmcnt queue undisturbed
        } else {
          nx = (s < S) ? reinterpret_cast<const int2*>(graph)[s]
                       : make_int2(N, N);  // cold fallback, ~never taken
        }
        seg_st = nx.x; seg_en = nx.y;
        // Overlapping start (degenerate duplicate chain): re-seed with row r.
        if (seg_st <= r) { acc = v; }
        else { acc = (f32x4){0.f, 0.f, 0.f, 0.f}; }
      }
    }
#pragma unroll
    for (int j = 0; j < GROUP; ++j) buf[j] = nbuf[j];
  }

  // Tail: current segment extends past the tile -> atomic partial.
  if (s < S && seg_st <= r1) {
    const float inv = 1.0f / (float)(seg_en - seg_st + 1);
    f32x4 res = acc * inv;
    if (seg_st >= r0) {  // EPS owner
      res += EPS_VAL;
    }
    float* op = out + (size_t)s * DIM + t * 4;
    unsafeAtomicAdd(op + 0, res.x);
    unsafeAtomicAdd(op + 1, res.y);
    unsafeAtomicAdd(op + 2, res.z);
    unsafeAtomicAdd(op + 3, res.w);
  }
}

extern "C" void kernel_launch(void* const* d_in, const int* in_sizes, int n_in,
                              void* d_out, int out_size, void* d_ws, size_t ws_size,
                              hipStream_t stream) {
  const float* x = (const float*)d_in[0];
  const int* graph = (const int*)d_in[1];
  float* out = (float*)d_out;
  int* lo_arr = (int*)d_ws;  // ntiles ints

  const int N = in_sizes[0] / DIM;
  const int S = in_sizes[1] / 2;
  const int ntiles = N / TILE;
  const int n4 = out_size / 4;

  const int init_items = (n4 > ntiles) ? n4 : ntiles;
  init_kernel<<<(init_items + 255) / 256, 256, 0, stream>>>(
      reinterpret_cast<f32x4*>(out), n4, graph, lo_arr, ntiles, S);

  pool_tile_kernel<<<ntiles, 128, 0, stream>>>(x, graph, lo_arr, out, N, S);
}